// Round 1
// baseline (247.420 us; speedup 1.0000x reference)
//
#include <hip/hip_runtime.h>
#include <hip/hip_fp16.h>

typedef unsigned short u16;
typedef __attribute__((ext_vector_type(4))) float f32x4;
typedef __attribute__((ext_vector_type(8))) short s16x8;

#define NTHREADS 256
#define B_SZ 2
#define N_SZ 2048
#define H_SZ 8
#define DK 64
#define DM 512

static __device__ inline void mfma_f16(f32x4& acc, s16x8 a, s16x8 b) {
    asm volatile("v_mfma_f32_16x16x32_f16 %0, %1, %2, %0" : "+v"(acc) : "v"(a), "v"(b));
}

static __device__ inline u16 f16_rn(float f) {
    __half h = __float2half(f);
    return __half_as_ushort(h);
}

static __device__ inline s16x8 cvt8(const float4& a, const float4& b) {
    s16x8 r;
    r[0] = (short)f16_rn(a.x); r[1] = (short)f16_rn(a.y);
    r[2] = (short)f16_rn(a.z); r[3] = (short)f16_rn(a.w);
    r[4] = (short)f16_rn(b.x); r[5] = (short)f16_rn(b.y);
    r[6] = (short)f16_rn(b.z); r[7] = (short)f16_rn(b.w);
    return r;
}

// ---------------------------------------------------------------------------
// K0a: transpose projections [3][H][512][64] fp32 -> Pt [3][H][64][512] fp16
// (so MFMA B-fragments read 8 contiguous K elements)
// ---------------------------------------------------------------------------
__global__ void __launch_bounds__(NTHREADS) k_prep_proj(
    const float* __restrict__ qp, const float* __restrict__ kp,
    const float* __restrict__ vp, u16* __restrict__ Pt) {
    int ddt = blockIdx.x, h = blockIdx.y, z = blockIdx.z;
    const float* src = (z == 0 ? qp : (z == 1 ? kp : vp)) + (size_t)h * DM * DK;
    u16* dst = Pt + ((size_t)(z * H_SZ + h)) * DK * DM;
    __shared__ float lds[64 * 65];
    int t = threadIdx.x;
#pragma unroll
    for (int i = 0; i < 16; i++) {
        int idx = i * 256 + t;
        int rr = idx >> 6, cc = idx & 63;   // rr = dd_local, cc = kk
        lds[cc * 65 + rr] = src[(size_t)(ddt * 64 + rr) * DK + cc];
    }
    __syncthreads();
#pragma unroll
    for (int i = 0; i < 16; i++) {
        int idx = i * 256 + t;
        int kk = idx >> 6, dd = idx & 63;
        dst[(size_t)kk * DM + ddt * 64 + dd] = f16_rn(lds[kk * 65 + dd]);
    }
}

// ---------------------------------------------------------------------------
// K0b: w_out fp32 [512][512] -> fp16 same layout (rows contiguous in c)
// ---------------------------------------------------------------------------
__global__ void __launch_bounds__(NTHREADS) k_cvt_wout(
    const float* __restrict__ w, u16* __restrict__ wb) {
    int i = (blockIdx.x * 256 + threadIdx.x) * 4;
    float4 f = *(const float4*)(w + i);
    ushort4 r;
    r.x = f16_rn(f.x); r.y = f16_rn(f.y); r.z = f16_rn(f.z); r.w = f16_rn(f.w);
    *(ushort4*)(wb + i) = r;
}

// ---------------------------------------------------------------------------
// K1: projection GEMM, grid.z selects q/k/v.
//   A [4096 x 512] fp32 staged->fp16 LDS; B = Pt fp16 (direct global frags).
//   z=0: Qb [b][h][n][dk] fp16 ; z=1: Kb same ; z=2: Vt 64x64 transposed tiles
// ---------------------------------------------------------------------------
__global__ void __launch_bounds__(NTHREADS) k_proj_gemm(
    const float* __restrict__ q, const float* __restrict__ k,
    const float* __restrict__ v, const u16* __restrict__ Pt,
    const float* __restrict__ qbias, const float* __restrict__ kbias,
    const float* __restrict__ vbias,
    u16* __restrict__ Qb, u16* __restrict__ Kb, u16* __restrict__ Vt) {
    int z = blockIdx.z;
    const float* A = z == 0 ? q : (z == 1 ? k : v);
    const float* bias = z == 0 ? qbias : (z == 1 ? kbias : vbias);
    const u16* Bw = Pt + (size_t)z * DM * DM;
    int m0 = blockIdx.x * 128, c0 = blockIdx.y * 64;
    int t = threadIdx.x, w = t >> 6, l = t & 63, g = l >> 4, cl = l & 15;
    __shared__ __align__(16) u16 a_lds[128 * 40];   // 32 elems + 8 pad per row
    f32x4 acc[2][4] = {};
    int arow = t >> 1, ahalf = t & 1;
    const float* asrc = A + (size_t)(m0 + arow) * DM + ahalf * 16;
    u16* awr = &a_lds[arow * 40 + ahalf * 16];
    for (int ks = 0; ks < 16; ks++) {
        float4 f0 = *(const float4*)(asrc + ks * 32 + 0);
        float4 f1 = *(const float4*)(asrc + ks * 32 + 4);
        float4 f2 = *(const float4*)(asrc + ks * 32 + 8);
        float4 f3 = *(const float4*)(asrc + ks * 32 + 12);
        s16x8 bfrag[4];
#pragma unroll
        for (int st = 0; st < 4; st++) {
            int c = c0 + st * 16 + cl;
            bfrag[st] = *(const s16x8*)(Bw + (size_t)c * DM + ks * 32 + 8 * g);
        }
        __syncthreads();
        *(s16x8*)(awr) = cvt8(f0, f1);
        *(s16x8*)(awr + 8) = cvt8(f2, f3);
        __syncthreads();
#pragma unroll
        for (int rs = 0; rs < 2; rs++) {
            s16x8 afrag = *(const s16x8*)&a_lds[(w * 32 + rs * 16 + cl) * 40 + 8 * g];
#pragma unroll
            for (int st = 0; st < 4; st++) mfma_f16(acc[rs][st], afrag, bfrag[st]);
        }
    }
#pragma unroll
    for (int rs = 0; rs < 2; rs++) {
#pragma unroll
        for (int st = 0; st < 4; st++) {
            int c = c0 + st * 16 + cl;
            int h = c >> 6, kk = c & 63;
            float bv = bias[c];
#pragma unroll
            for (int r = 0; r < 4; r++) {
                int m = m0 + w * 32 + rs * 16 + 4 * g + r;
                int b = m >> 11, n = m & 2047;
                u16 o = f16_rn(acc[rs][st][r] + bv);
                if (z == 2) {
                    // transposed 64x64 tiles: [bh][n/64][d=kk][j=n%64]
                    Vt[((size_t)((b * H_SZ + h) * 32 + (n >> 6))) * 4096 + kk * 64 + (n & 63)] = o;
                } else {
                    u16* dst = (z == 0) ? Qb : Kb;
                    dst[((size_t)(b * H_SZ + h) * N_SZ + n) * DK + kk] = o;
                }
            }
        }
    }
}

// ---------------------------------------------------------------------------
// K2: fused attention.  grid (N/64, H, B); 256 threads = 4 waves, each wave
// owns 16 q-rows.  Per 64-col K/V tile: S via MFMA, RBF+|S|*beta*Rnorm,
// online softmax (16-lane shfl groups), P->LDS fp16, PV via MFMA.
// Output written directly in O_mat layout [b*N+n][d*8+h] fp32.
// ---------------------------------------------------------------------------
__global__ void __launch_bounds__(NTHREADS) k_attn(
    const u16* __restrict__ Qb, const u16* __restrict__ Kb,
    const u16* __restrict__ Vt, const float* __restrict__ coords,
    const unsigned char* __restrict__ maskp,
    const float* __restrict__ spread_w, const float* __restrict__ beta_w,
    float* __restrict__ Omat) {
    int qt = blockIdx.x, h = blockIdx.y, b = blockIdx.z;
    int n0 = qt * 64;
    int t = threadIdx.x, w = t >> 6, l = t & 63, g = l >> 4, cl = l & 15;
    int bh = b * H_SZ + h;
    __shared__ __align__(16) u16 k_lds[64 * 72];
    __shared__ __align__(16) u16 v_lds[64 * 72];
    __shared__ __align__(16) u16 p_lds[4][16 * 72];
    __shared__ float cj[64 * 4];
    __shared__ unsigned char msk[64];

    int qrow = n0 + w * 16 + cl;
    const u16* qp = Qb + ((size_t)bh * N_SZ + qrow) * DK;
    s16x8 qf0 = *(const s16x8*)(qp + 8 * g);
    s16x8 qf1 = *(const s16x8*)(qp + 32 + 8 * g);

    float qcx[4], qcy[4], qcz[4];
#pragma unroll
    for (int r = 0; r < 4; r++) {
        int row = n0 + w * 16 + 4 * g + r;
        const float* cp = coords + ((size_t)b * N_SZ + row) * 3;
        qcx[r] = cp[0]; qcy[r] = cp[1]; qcz[r] = cp[2];
    }
    float sigma = 2.0f + __expf(spread_w[h]);
    float ninv = -1.0f / (2.0f * sigma * sigma);
    float beta = __expf(beta_w[h]);

    float mrun[4] = {-1e30f, -1e30f, -1e30f, -1e30f};
    float lsum[4] = {0.f, 0.f, 0.f, 0.f};
    f32x4 oacc[4] = {};
    int srow = t >> 2, sq = t & 3;

    for (int jt = 0; jt < 32; jt++) {
        int j0 = jt * 64;
        __syncthreads();
        {
            const u16* ksrc = Kb + ((size_t)bh * N_SZ + j0 + srow) * DK + sq * 16;
            *(s16x8*)&k_lds[srow * 72 + sq * 16 + 0] = *(const s16x8*)(ksrc);
            *(s16x8*)&k_lds[srow * 72 + sq * 16 + 8] = *(const s16x8*)(ksrc + 8);
            const u16* vsrc = Vt + ((size_t)(bh * 32 + jt)) * 4096 + srow * 64 + sq * 16;
            *(s16x8*)&v_lds[srow * 72 + sq * 16 + 0] = *(const s16x8*)(vsrc);
            *(s16x8*)&v_lds[srow * 72 + sq * 16 + 8] = *(const s16x8*)(vsrc + 8);
            if (t < 64) {
                const float* cp = coords + ((size_t)b * N_SZ + j0 + t) * 3;
                cj[t * 4] = cp[0]; cj[t * 4 + 1] = cp[1]; cj[t * 4 + 2] = cp[2];
                msk[t] = maskp[b * N_SZ + j0 + t];
            }
        }
        __syncthreads();

        f32x4 s[4];
#pragma unroll
        for (int st = 0; st < 4; st++) {
            int jj = st * 16 + cl;
            s16x8 kf0 = *(const s16x8*)&k_lds[jj * 72 + 8 * g];
            s16x8 kf1 = *(const s16x8*)&k_lds[jj * 72 + 32 + 8 * g];
            f32x4 a = {};
            mfma_f16(a, qf0, kf0);
            mfma_f16(a, qf1, kf1);
            s[st] = a;
        }

        float sr[4][4];
#pragma unroll
        for (int st = 0; st < 4; st++) {
            int jj = st * 16 + cl;
            float cx = cj[jj * 4], cy = cj[jj * 4 + 1], cz = cj[jj * 4 + 2];
            bool mk = msk[jj] != 0;
#pragma unroll
            for (int r = 0; r < 4; r++) {
                float sv = s[st][r] * 0.125f;        // 1/sqrt(64)
                float dx = qcx[r] - cx, dy = qcy[r] - cy, dz = qcz[r] - cz;
                float d2 = dx * dx + dy * dy + dz * dz;
                float rb = __expf(d2 * ninv);
                float rn = fmaf(2.002002f, rb, -1.002002f);  // 2(R-.001)/.999 - 1
                sv = fmaf(fabsf(sv) * beta, rn, sv);
                sr[st][r] = mk ? -1e30f : sv;
            }
        }
        // online softmax: rows live in 16-lane groups
#pragma unroll
        for (int r = 0; r < 4; r++) {
            float tm = fmaxf(fmaxf(sr[0][r], sr[1][r]), fmaxf(sr[2][r], sr[3][r]));
            tm = fmaxf(tm, __shfl_xor(tm, 1));
            tm = fmaxf(tm, __shfl_xor(tm, 2));
            tm = fmaxf(tm, __shfl_xor(tm, 4));
            tm = fmaxf(tm, __shfl_xor(tm, 8));
            float mn = fmaxf(mrun[r], tm);
            float corr = __expf(mrun[r] - mn);
            mrun[r] = mn;
            lsum[r] *= corr;
#pragma unroll
            for (int dst = 0; dst < 4; dst++) oacc[dst][r] *= corr;
        }
#pragma unroll
        for (int st = 0; st < 4; st++) {
#pragma unroll
            for (int r = 0; r < 4; r++) {
                float p = __expf(sr[st][r] - mrun[r]);
                lsum[r] += p;
                p_lds[w][(4 * g + r) * 72 + st * 16 + cl] = f16_rn(p);
            }
        }
#pragma unroll
        for (int kstep = 0; kstep < 2; kstep++) {
            s16x8 pf = *(const s16x8*)&p_lds[w][cl * 72 + kstep * 32 + 8 * g];
#pragma unroll
            for (int dst = 0; dst < 4; dst++) {
                s16x8 vf = *(const s16x8*)&v_lds[(dst * 16 + cl) * 72 + kstep * 32 + 8 * g];
                mfma_f16(oacc[dst], pf, vf);
            }
        }
    }
#pragma unroll
    for (int r = 0; r < 4; r++) {
        float s = lsum[r];
        s += __shfl_xor(s, 1); s += __shfl_xor(s, 2);
        s += __shfl_xor(s, 4); s += __shfl_xor(s, 8);
        lsum[r] = 1.0f / s;
    }
#pragma unroll
    for (int dst = 0; dst < 4; dst++) {
#pragma unroll
        for (int r = 0; r < 4; r++) {
            int row = n0 + w * 16 + 4 * g + r;
            int col = (dst * 16 + cl) * 8 + h;     // c = k*H + h
            Omat[((size_t)b * N_SZ + row) * DM + col] = oacc[dst][r] * lsum[r];
        }
    }
}

// ---------------------------------------------------------------------------
// K3: out = O_mat [4096x512] @ w_out^T  (B-frag rows of w_out contiguous in c)
// ---------------------------------------------------------------------------
__global__ void __launch_bounds__(NTHREADS) k_out_gemm(
    const float* __restrict__ Omat, const u16* __restrict__ Wb,
    float* __restrict__ out) {
    int m0 = blockIdx.x * 128, c0 = blockIdx.y * 64;
    int t = threadIdx.x, w = t >> 6, l = t & 63, g = l >> 4, cl = l & 15;
    __shared__ __align__(16) u16 a_lds[128 * 40];
    f32x4 acc[2][4] = {};
    int arow = t >> 1, ahalf = t & 1;
    const float* asrc = Omat + (size_t)(m0 + arow) * DM + ahalf * 16;
    u16* awr = &a_lds[arow * 40 + ahalf * 16];
    for (int ks = 0; ks < 16; ks++) {
        float4 f0 = *(const float4*)(asrc + ks * 32 + 0);
        float4 f1 = *(const float4*)(asrc + ks * 32 + 4);
        float4 f2 = *(const float4*)(asrc + ks * 32 + 8);
        float4 f3 = *(const float4*)(asrc + ks * 32 + 12);
        s16x8 bfrag[4];
#pragma unroll
        for (int st = 0; st < 4; st++) {
            int c = c0 + st * 16 + cl;
            bfrag[st] = *(const s16x8*)(Wb + (size_t)c * DM + ks * 32 + 8 * g);
        }
        __syncthreads();
        *(s16x8*)(awr) = cvt8(f0, f1);
        *(s16x8*)(awr + 8) = cvt8(f2, f3);
        __syncthreads();
#pragma unroll
        for (int rs = 0; rs < 2; rs++) {
            s16x8 afrag = *(const s16x8*)&a_lds[(w * 32 + rs * 16 + cl) * 40 + 8 * g];
#pragma unroll
            for (int st = 0; st < 4; st++) mfma_f16(acc[rs][st], afrag, bfrag[st]);
        }
    }
#pragma unroll
    for (int rs = 0; rs < 2; rs++) {
#pragma unroll
        for (int st = 0; st < 4; st++) {
            int c = c0 + st * 16 + cl;
#pragma unroll
            for (int r = 0; r < 4; r++) {
                int m = m0 + w * 32 + rs * 16 + 4 * g + r;
                out[(size_t)m * DM + c] = acc[rs][st][r];
            }
        }
    }
}

extern "C" void kernel_launch(void* const* d_in, const int* in_sizes, int n_in,
                              void* d_out, int out_size, void* d_ws, size_t ws_size,
                              hipStream_t stream) {
    const float* q      = (const float*)d_in[0];
    const float* k      = (const float*)d_in[1];
    const float* v      = (const float*)d_in[2];
    const float* coords = (const float*)d_in[3];
    const unsigned char* mask = (const unsigned char*)d_in[4];
    const float* sw     = (const float*)d_in[5];
    const float* bw     = (const float*)d_in[6];
    const float* qp     = (const float*)d_in[7];
    const float* kp     = (const float*)d_in[8];
    const float* vp     = (const float*)d_in[9];
    const float* qbias  = (const float*)d_in[10];
    const float* kbias  = (const float*)d_in[11];
    const float* vbias  = (const float*)d_in[12];
    const float* wo     = (const float*)d_in[13];

    char* ws = (char*)d_ws;
    u16*   Pt   = (u16*)(ws);                    // 3*512*512*2   = 1,572,864 B
    u16*   Wb   = (u16*)(ws + 1572864);          // 512*512*2     =   524,288 B
    u16*   Qb   = (u16*)(ws + 2097152);          // 2M elems fp16 = 4,194,304 B
    u16*   Kb   = (u16*)(ws + 6291456);          // 4,194,304 B
    u16*   Vt   = (u16*)(ws + 10485760);         // 4,194,304 B
    float* Omat = (float*)(ws + 14680064);       // 8,388,608 B  (total ~23 MB)

    k_prep_proj<<<dim3(8, 8, 3), NTHREADS, 0, stream>>>(qp, kp, vp, Pt);
    k_cvt_wout<<<dim3(256), NTHREADS, 0, stream>>>(wo, Wb);
    k_proj_gemm<<<dim3(32, 8, 3), NTHREADS, 0, stream>>>(q, k, v, Pt, qbias, kbias, vbias, Qb, Kb, Vt);
    k_attn<<<dim3(32, 8, 2), NTHREADS, 0, stream>>>(Qb, Kb, Vt, coords, mask, sw, bw, Omat);
    k_out_gemm<<<dim3(32, 8), NTHREADS, 0, stream>>>(Omat, Wb, (float*)d_out);
}

// Round 2
// 215.949 us; speedup vs baseline: 1.1457x; 1.1457x over previous
//
#include <hip/hip_runtime.h>
#include <hip/hip_fp16.h>

typedef unsigned short u16;
typedef __attribute__((ext_vector_type(4))) float f32x4;
typedef __attribute__((ext_vector_type(8))) short s16x8;

#define B_SZ 2
#define N_SZ 2048
#define H_SZ 8
#define DK 64
#define DM 512

static __device__ inline void mfma_f16(f32x4& acc, s16x8 a, s16x8 b) {
    asm volatile("v_mfma_f32_16x16x32_f16 %0, %1, %2, %0" : "+v"(acc) : "v"(a), "v"(b));
}
static __device__ inline u16 f16_rn(float f) { return __half_as_ushort(__float2half(f)); }

static __device__ inline s16x8 cvt8(const float4& a, const float4& b) {
    s16x8 r;
    r[0] = (short)f16_rn(a.x); r[1] = (short)f16_rn(a.y);
    r[2] = (short)f16_rn(a.z); r[3] = (short)f16_rn(a.w);
    r[4] = (short)f16_rn(b.x); r[5] = (short)f16_rn(b.y);
    r[6] = (short)f16_rn(b.z); r[7] = (short)f16_rn(b.w);
    return r;
}

// G4 XOR swizzle for 128B rows: byte ^= (row&7)<<4. Bijective within 8-row
// stripe; spreads the 16-row b128 column read across 8 distinct 16B slots.
static __device__ inline u16* swz(u16* base, int row, int byteoff) {
    return (u16*)((char*)base + row * 128 + (byteoff ^ ((row & 7) << 4)));
}
static __device__ inline const u16* swzc(const u16* base, int row, int byteoff) {
    return (const u16*)((const char*)base + row * 128 + (byteoff ^ ((row & 7) << 4)));
}

#if __has_builtin(__builtin_amdgcn_global_load_lds)
#define HAS_GLL 1
static __device__ inline void gll16(const u16* g, u16* l) {
    __builtin_amdgcn_global_load_lds(
        (const __attribute__((address_space(1))) unsigned int*)g,
        (__attribute__((address_space(3))) unsigned int*)l, 16, 0, 0);
}
#endif

// Stage 16B/lane: builtin path writes lds_base + lane*16 (wave-uniform base);
// fallback does the same layout via reg round-trip.
static __device__ inline void stage16(const u16* gp, u16* lbase, int lane) {
#ifdef HAS_GLL
    gll16(gp, lbase);
#else
    *(s16x8*)(lbase + lane * 8) = *(const s16x8*)(gp);
#endif
}

// ---------------------------------------------------------------------------
// K0: all conversions in one kernel.
//  blk 0..191   : proj transpose -> Pt [(z*8+h)*64+kk][512] fp16
//  blk 192..447 : w_out fp32 -> Wb fp16
//  blk 448..3519: q,k,v fp32 -> Af [z][4096][512] fp16
// ---------------------------------------------------------------------------
__global__ void __launch_bounds__(256) k_prep(
    const float* __restrict__ q, const float* __restrict__ k,
    const float* __restrict__ v, const float* __restrict__ qp,
    const float* __restrict__ kp, const float* __restrict__ vp,
    const float* __restrict__ wo,
    u16* __restrict__ Pt, u16* __restrict__ Wb, u16* __restrict__ Af) {
    int blk = blockIdx.x, t = threadIdx.x;
    __shared__ float lds[64 * 65];
    if (blk < 192) {
        int z = blk >> 6, rem = blk & 63, h = rem >> 3, ddt = rem & 7;
        const float* src = (z == 0 ? qp : (z == 1 ? kp : vp)) + (size_t)h * DM * DK;
        u16* dst = Pt + ((size_t)(z * H_SZ + h)) * DK * DM;
#pragma unroll
        for (int i = 0; i < 16; i++) {
            int idx = i * 256 + t;
            int rr = idx >> 6, cc = idx & 63;
            lds[cc * 65 + rr] = src[(size_t)(ddt * 64 + rr) * DK + cc];
        }
        __syncthreads();
#pragma unroll
        for (int i = 0; i < 16; i++) {
            int idx = i * 256 + t;
            int kk = idx >> 6, dd = idx & 63;
            dst[(size_t)kk * DM + ddt * 64 + dd] = f16_rn(lds[kk * 65 + dd]);
        }
    } else if (blk < 448) {
        int i = (blk - 192) * 1024 + t * 4;
        float4 f = *(const float4*)(wo + i);
        ushort4 r;
        r.x = f16_rn(f.x); r.y = f16_rn(f.y); r.z = f16_rn(f.z); r.w = f16_rn(f.w);
        *(ushort4*)(Wb + i) = r;
    } else {
        size_t base = (size_t)(blk - 448) * 2048 + (size_t)t * 8;
        int z = (int)(base >> 21);
        size_t off = base & 2097151;
        const float* s = (z == 0 ? q : (z == 1 ? k : v)) + off;
        float4 f0 = *(const float4*)(s);
        float4 f1 = *(const float4*)(s + 4);
        *(s16x8*)(Af + base) = cvt8(f0, f1);
    }
}

// ---------------------------------------------------------------------------
// K1: projection GEMM (z = q/k/v). A fp16 via global_load_lds (src-swizzled),
// B = Pt direct from global (L2-resident). M=128, N=64, BK=64.
//  z=0: Qb scaled by 0.125 (folds 1/sqrt(dk)); z=2: Vt 64x64 transposed tiles.
// ---------------------------------------------------------------------------
__global__ void __launch_bounds__(256) k_proj_gemm(
    const u16* __restrict__ Af, const u16* __restrict__ Pt,
    const float* __restrict__ qbias, const float* __restrict__ kbias,
    const float* __restrict__ vbias,
    u16* __restrict__ Qb, u16* __restrict__ Kb, u16* __restrict__ Vt) {
    int z = blockIdx.z;
    const u16* A = Af + (size_t)z * (4096 * 512);
    const float* bias = z == 0 ? qbias : (z == 1 ? kbias : vbias);
    const u16* Bw = Pt + (size_t)z * (512 * 512);
    int m0 = blockIdx.x * 128, c0 = blockIdx.y * 64;
    int t = threadIdx.x, w = t >> 6, l = t & 63, g = (l >> 4), cl = l & 15;
    __shared__ __align__(16) u16 a_lds[128 * 64];
    f32x4 acc[2][4] = {};
    int srow_b = w * 8 + (l >> 3), schk = l & 7;
    for (int ks = 0; ks < 8; ks++) {
        __syncthreads();
#pragma unroll
        for (int cc = 0; cc < 4; cc++) {
            int row = cc * 32 + srow_b;
            const u16* gp = A + (size_t)(m0 + row) * 512 + ks * 64 + ((schk ^ (row & 7)) << 3);
            stage16(gp, a_lds + cc * 2048 + w * 512, l);
        }
        s16x8 bfrag[4][2];
#pragma unroll
        for (int st = 0; st < 4; st++) {
            int c = c0 + st * 16 + cl;
#pragma unroll
            for (int kk = 0; kk < 2; kk++)
                bfrag[st][kk] = *(const s16x8*)(Bw + (size_t)c * 512 + ks * 64 + kk * 32 + 8 * g);
        }
        __syncthreads();
#pragma unroll
        for (int rs = 0; rs < 2; rs++) {
            int row = w * 32 + rs * 16 + cl;
#pragma unroll
            for (int kk = 0; kk < 2; kk++) {
                s16x8 afrag = *(const s16x8*)swzc(a_lds, row, kk * 64 + 16 * g);
#pragma unroll
                for (int st = 0; st < 4; st++) mfma_f16(acc[rs][st], afrag, bfrag[st][kk]);
            }
        }
    }
    float sc = (z == 0) ? 0.125f : 1.0f;
#pragma unroll
    for (int rs = 0; rs < 2; rs++) {
#pragma unroll
        for (int st = 0; st < 4; st++) {
            int c = c0 + st * 16 + cl;
            int h = c >> 6, kk = c & 63;
            float bv = bias[c];
#pragma unroll
            for (int r = 0; r < 4; r++) {
                int m = m0 + w * 32 + rs * 16 + 4 * g + r;
                int b = m >> 11, n = m & 2047;
                u16 o = f16_rn((acc[rs][st][r] + bv) * sc);
                if (z == 2) {
                    Vt[((size_t)((b * H_SZ + h) * 32 + (n >> 6))) * 4096 + kk * 64 + (n & 63)] = o;
                } else {
                    u16* dst = (z == 0) ? Qb : Kb;
                    dst[((size_t)(b * H_SZ + h) * N_SZ + n) * DK + kk] = o;
                }
            }
        }
    }
}

// ---------------------------------------------------------------------------
// K2: fused attention. 512 threads = 8 waves; waves 0-3 (half 0) take even
// j-tiles, waves 4-7 odd, same 64 q-rows; per-half K/V LDS (XOR-swizzled),
// end merge of (m,l,O) in LDS scratch. XCD-chunked block swizzle.
// Emits Omat fp16 [b*N+n][d*8+h].
// ---------------------------------------------------------------------------
__global__ void __launch_bounds__(512, 4) k_attn(
    const u16* __restrict__ Qb, const u16* __restrict__ Kb,
    const u16* __restrict__ Vt, const float* __restrict__ coords,
    const unsigned char* __restrict__ maskp,
    const float* __restrict__ spread_w, const float* __restrict__ beta_w,
    u16* __restrict__ Om) {
    int bid = blockIdx.x;
    int wid = (bid & 7) * 64 + (bid >> 3);      // XCD-chunked (512 % 8 == 0)
    int qt = wid & 31, bh = wid >> 5;
    int h = bh & 7, b = bh >> 3;
    int n0 = qt * 64;
    int t = threadIdx.x, w = t >> 6, l = t & 63, g = (l >> 4), cl = l & 15;
    int wq = w & 3, half = w >> 2;
    __shared__ __align__(16) u16 kbuf[2][4096];
    __shared__ __align__(16) u16 vbuf[2][4096];
    __shared__ __align__(16) u16 pbuf[8][1024];
    __shared__ float cjs[2][64][4];
    __shared__ unsigned char msks[2][64];

    int qrow = n0 + wq * 16 + cl;
    const u16* qp = Qb + ((size_t)bh * N_SZ + qrow) * DK;
    s16x8 qf0 = *(const s16x8*)(qp + 8 * g);
    s16x8 qf1 = *(const s16x8*)(qp + 32 + 8 * g);

    float qcx[4], qcy[4], qcz[4];
#pragma unroll
    for (int r = 0; r < 4; r++) {
        int row = n0 + wq * 16 + 4 * g + r;
        const float* cp = coords + ((size_t)b * N_SZ + row) * 3;
        qcx[r] = cp[0]; qcy[r] = cp[1]; qcz[r] = cp[2];
    }
    float sigma = 2.0f + __expf(spread_w[h]);
    float ninv = -1.0f / (2.0f * sigma * sigma);
    float beta = __expf(beta_w[h]);

    float mrun[4] = {-1e30f, -1e30f, -1e30f, -1e30f};
    float lsum[4] = {0.f, 0.f, 0.f, 0.f};
    f32x4 oacc[4] = {};
    int sid = t & 255, shalf = t >> 8, srow = sid >> 2, sq = sid & 3;
    const u16* kbase = Kb + (size_t)bh * N_SZ * DK;
    const u16* vbase = Vt + (size_t)bh * 32 * 4096;

    for (int it = 0; it < 16; it++) {
        int jts = it * 2 + shalf, j0s = jts * 64;
        __syncthreads();
        {
            const u16* ksrc = kbase + (size_t)(j0s + srow) * 64 + sq * 16;
            *(s16x8*)swz(kbuf[shalf], srow, sq * 32)      = *(const s16x8*)(ksrc);
            *(s16x8*)swz(kbuf[shalf], srow, sq * 32 + 16) = *(const s16x8*)(ksrc + 8);
            const u16* vsrc = vbase + (size_t)jts * 4096 + srow * 64 + sq * 16;
            *(s16x8*)swz(vbuf[shalf], srow, sq * 32)      = *(const s16x8*)(vsrc);
            *(s16x8*)swz(vbuf[shalf], srow, sq * 32 + 16) = *(const s16x8*)(vsrc + 8);
            if (sid < 64) {
                const float* cp = coords + ((size_t)b * N_SZ + j0s + sid) * 3;
                cjs[shalf][sid][0] = cp[0];
                cjs[shalf][sid][1] = cp[1];
                cjs[shalf][sid][2] = cp[2];
                msks[shalf][sid] = maskp[b * N_SZ + j0s + sid];
            }
        }
        __syncthreads();

        f32x4 s[4];
#pragma unroll
        for (int st = 0; st < 4; st++) {
            int jj = st * 16 + cl;
            s16x8 kf0 = *(const s16x8*)swzc(kbuf[half], jj, 16 * g);
            s16x8 kf1 = *(const s16x8*)swzc(kbuf[half], jj, 64 + 16 * g);
            f32x4 a = {};
            mfma_f16(a, qf0, kf0);
            mfma_f16(a, qf1, kf1);
            s[st] = a;
        }
        float sr[4][4];
#pragma unroll
        for (int st = 0; st < 4; st++) {
            int jj = st * 16 + cl;
            float cx = cjs[half][jj][0], cy = cjs[half][jj][1], cz = cjs[half][jj][2];
            bool mk = msks[half][jj] != 0;
#pragma unroll
            for (int r = 0; r < 4; r++) {
                float sv = s[st][r];                 // already scaled by 1/8
                float dx = qcx[r] - cx, dy = qcy[r] - cy, dz = qcz[r] - cz;
                float d2 = fmaf(dx, dx, fmaf(dy, dy, dz * dz));
                float rb = __expf(d2 * ninv);
                float rn = fmaf(2.002002f, rb, -1.002002f);
                sv = fmaf(fabsf(sv) * beta, rn, sv);
                sr[st][r] = mk ? -1e30f : sv;
            }
        }
        // row max (16-lane groups) + defer-max (T13, thr=8)
        float tmx[4]; int need = 0;
#pragma unroll
        for (int r = 0; r < 4; r++) {
            float tm = fmaxf(fmaxf(sr[0][r], sr[1][r]), fmaxf(sr[2][r], sr[3][r]));
            tm = fmaxf(tm, __shfl_xor(tm, 1));
            tm = fmaxf(tm, __shfl_xor(tm, 2));
            tm = fmaxf(tm, __shfl_xor(tm, 4));
            tm = fmaxf(tm, __shfl_xor(tm, 8));
            tmx[r] = tm;
            if (tm > mrun[r] + 8.0f) need = 1;
        }
        if (__any(need)) {
#pragma unroll
            for (int r = 0; r < 4; r++) {
                float mn = fmaxf(mrun[r], tmx[r]);
                float corr = __expf(mrun[r] - mn);
                mrun[r] = mn;
                lsum[r] *= corr;
#pragma unroll
                for (int dst = 0; dst < 4; dst++) oacc[dst][r] *= corr;
            }
        }
#pragma unroll
        for (int st = 0; st < 4; st++) {
#pragma unroll
            for (int r = 0; r < 4; r++) {
                float p = __expf(sr[st][r] - mrun[r]);   // bounded by e^8
                lsum[r] += p;
                int row = 4 * g + r;
                *swz(pbuf[w], row, (st * 16 + cl) * 2) = f16_rn(p);
            }
        }
#pragma unroll
        for (int kstep = 0; kstep < 2; kstep++) {
            s16x8 pf = *(const s16x8*)swzc(pbuf[w], cl, kstep * 64 + 16 * g);
#pragma unroll
            for (int dst = 0; dst < 4; dst++) {
                s16x8 vf = *(const s16x8*)swzc(vbuf[half], dst * 16 + cl, kstep * 64 + 16 * g);
                mfma_f16(oacc[dst], pf, vf);
            }
        }
    }
    // full row-sum of l
#pragma unroll
    for (int r = 0; r < 4; r++) {
        float s = lsum[r];
        s += __shfl_xor(s, 1); s += __shfl_xor(s, 2);
        s += __shfl_xor(s, 4); s += __shfl_xor(s, 8);
        lsum[r] = s;
    }
    // merge the two j-halves through LDS scratch (aliases kbuf/vbuf)
    __syncthreads();
    float* scrO = (float*)(&kbuf[0][0]);   // [wq][16][64] fp32 = 16 KiB
    float* scrM = (float*)(&vbuf[0][0]);   // [wq][2][16]
    if (half == 1) {
#pragma unroll
        for (int r = 0; r < 4; r++) {
            int rr = 4 * g + r;
#pragma unroll
            for (int dst = 0; dst < 4; dst++)
                scrO[wq * 1024 + rr * 64 + dst * 16 + cl] = oacc[dst][r];
            if (cl == 0) {
                scrM[wq * 32 + rr] = mrun[r];
                scrM[wq * 32 + 16 + rr] = lsum[r];
            }
        }
    }
    __syncthreads();
    if (half == 0) {
#pragma unroll
        for (int r = 0; r < 4; r++) {
            int rr = 4 * g + r;
            float mu = scrM[wq * 32 + rr], lu = scrM[wq * 32 + 16 + rr];
            float M = fmaxf(mrun[r], mu);
            float pa = __expf(mrun[r] - M), pb = __expf(mu - M);
            float inv = 1.0f / (pa * lsum[r] + pb * lu);
            int row = n0 + wq * 16 + rr;
#pragma unroll
            for (int dst = 0; dst < 4; dst++) {
                float o = (pa * oacc[dst][r] + pb * scrO[wq * 1024 + rr * 64 + dst * 16 + cl]) * inv;
                Om[((size_t)b * N_SZ + row) * DM + (dst * 16 + cl) * 8 + h] = f16_rn(o);
            }
        }
    }
}

// ---------------------------------------------------------------------------
// K3: out = Omat(fp16) @ w_out^T. M=64, N=64, BK=64, A via global_load_lds.
// ---------------------------------------------------------------------------
__global__ void __launch_bounds__(256) k_out_gemm(
    const u16* __restrict__ Om, const u16* __restrict__ Wb,
    float* __restrict__ out) {
    int m0 = blockIdx.x * 64, c0 = blockIdx.y * 64;
    int t = threadIdx.x, w = t >> 6, l = t & 63, g = (l >> 4), cl = l & 15;
    __shared__ __align__(16) u16 a_lds[64 * 64];
    f32x4 acc[4] = {};
    int srow_b = w * 8 + (l >> 3), schk = l & 7;
    for (int ks = 0; ks < 8; ks++) {
        __syncthreads();
#pragma unroll
        for (int cc = 0; cc < 2; cc++) {
            int row = cc * 32 + srow_b;
            const u16* gp = Om + (size_t)(m0 + row) * 512 + ks * 64 + ((schk ^ (row & 7)) << 3);
            stage16(gp, a_lds + cc * 2048 + w * 512, l);
        }
        s16x8 bfrag[4][2];
#pragma unroll
        for (int st = 0; st < 4; st++) {
            int c = c0 + st * 16 + cl;
#pragma unroll
            for (int kk = 0; kk < 2; kk++)
                bfrag[st][kk] = *(const s16x8*)(Wb + (size_t)c * 512 + ks * 64 + kk * 32 + 8 * g);
        }
        __syncthreads();
        int row = w * 16 + cl;
#pragma unroll
        for (int kk = 0; kk < 2; kk++) {
            s16x8 afrag = *(const s16x8*)swzc(a_lds, row, kk * 64 + 16 * g);
#pragma unroll
            for (int st = 0; st < 4; st++) mfma_f16(acc[st], afrag, bfrag[st][kk]);
        }
    }
#pragma unroll
    for (int st = 0; st < 4; st++) {
        int c = c0 + st * 16 + cl;
#pragma unroll
        for (int r = 0; r < 4; r++) {
            int m = m0 + w * 16 + 4 * g + r;
            out[(size_t)m * 512 + c] = acc[st][r];
        }
    }
}

extern "C" void kernel_launch(void* const* d_in, const int* in_sizes, int n_in,
                              void* d_out, int out_size, void* d_ws, size_t ws_size,
                              hipStream_t stream) {
    const float* q      = (const float*)d_in[0];
    const float* k      = (const float*)d_in[1];
    const float* v      = (const float*)d_in[2];
    const float* coords = (const float*)d_in[3];
    const unsigned char* mask = (const unsigned char*)d_in[4];
    const float* sw     = (const float*)d_in[5];
    const float* bw     = (const float*)d_in[6];
    const float* qp     = (const float*)d_in[7];
    const float* kp     = (const float*)d_in[8];
    const float* vp     = (const float*)d_in[9];
    const float* qbias  = (const float*)d_in[10];
    const float* kbias  = (const float*)d_in[11];
    const float* vbias  = (const float*)d_in[12];
    const float* wo     = (const float*)d_in[13];

    char* ws = (char*)d_ws;
    u16* Pt = (u16*)(ws);                    //  1,572,864 B
    u16* Wb = (u16*)(ws + 1572864);          //    524,288 B
    u16* Af = (u16*)(ws + 2097152);          // 12,582,912 B
    u16* Qb = (u16*)(ws + 14680064);         //  4,194,304 B
    u16* Kb = (u16*)(ws + 18874368);         //  4,194,304 B
    u16* Vt = (u16*)(ws + 23068672);         //  4,194,304 B
    u16* Om = (u16*)(ws + 27262976);         //  4,194,304 B (total ~31.5 MB)

    k_prep<<<dim3(3520), 256, 0, stream>>>(q, k, v, qp, kp, vp, wo, Pt, Wb, Af);
    k_proj_gemm<<<dim3(32, 8, 3), 256, 0, stream>>>(Af, Pt, qbias, kbias, vbias, Qb, Kb, Vt);
    k_attn<<<dim3(512), 512, 0, stream>>>(Qb, Kb, Vt, coords, mask, sw, bw, Om);
    k_out_gemm<<<dim3(64, 8), 256, 0, stream>>>(Om, Wb, (float*)d_out);
}